// Round 7
// baseline (10114.565 us; speedup 1.0000x reference)
//
#include <hip/hip_runtime.h>

// ConvGRU: 2-layer GRU, B=32, T=512, D=H=512, fp32 in/out, bf16 MFMA compute.
// Round-7: leader-broadcast barriers + per-layer domains + free-running waves.
//  - Write-once rings for h/hr (atomic bypass publish, cached cold-miss read).
//  - Per-block monotonic arrival slot; per-layer leader wave min-reduces its
//    32 slots and publishes ONE progress word; consumers poll that word with
//    <=2 lanes. No __syncthreads in the steady loop; u passes via LDS mailbox.
//  - Layer 1 chases layer-0 progress through the rings (run-ahead safe).

#define Bn 32
#define Tn 512
#define Dn 512
#define Hn 512
#define KKn 1024
#define NBLK 64
#define NTHR 256
#define NTHREADS (NBLK * NTHR)
#define RING (Tn + 2)

typedef __bf16 bf16x8 __attribute__((ext_vector_type(8)));
typedef float floatx4 __attribute__((ext_vector_type(4)));

// ---- persistent device state ----
__device__ unsigned short g_h0R[RING][Bn * Hn];
__device__ unsigned short g_h1R[RING][Bn * Hn];
__device__ unsigned short g_hr0R[RING][Bn * Hn];
__device__ unsigned short g_hr1R[RING][Bn * Hn];
__device__ unsigned short g_Xproj[3][Tn][32][Bn * 16]; // [g][t][ntile][b*16+lo]
__device__ unsigned short g_Wxb[3][Dn * Hn];           // layer0 x-half weights
__device__ unsigned long long g_slot[2][32];           // per-layer arrival slots
__device__ unsigned long long g_bcast[2][8];           // per-layer progress word
__device__ unsigned long long g_islot[NBLK * 8];       // init barrier slots

__device__ __forceinline__ bf16x8 ldb8(const unsigned short* p) {
    return *reinterpret_cast<const bf16x8*>(p);
}
__device__ __forceinline__ unsigned short f2b(float f) {
    union { float f; unsigned u; } v; v.f = f;
    unsigned u = v.u;
    return (unsigned short)((u + 0x7fffu + ((u >> 16) & 1u)) >> 16);  // RNE
}
__device__ __forceinline__ float b2fs(unsigned short b) {
    union { unsigned u; float f; } v; v.u = ((unsigned)b) << 16; return v.f;
}
__device__ __forceinline__ unsigned long long ald8(const void* p) {
    return __hip_atomic_load((const unsigned long long*)p, __ATOMIC_RELAXED,
                             __HIP_MEMORY_SCOPE_AGENT);
}
__device__ __forceinline__ void ast8(void* p, unsigned long long v) {
    __hip_atomic_store((unsigned long long*)p, v, __ATOMIC_RELAXED,
                       __HIP_MEMORY_SCOPE_AGENT);
}
__device__ __forceinline__ void ast4u(unsigned* p, unsigned v) {
    __hip_atomic_store(p, v, __ATOMIC_RELAXED, __HIP_MEMORY_SCOPE_AGENT);
}
__device__ __forceinline__ floatx4 mfma(bf16x8 a, bf16x8 b, floatx4 c) {
    return __builtin_amdgcn_mfma_f32_16x16x32_bf16(a, b, c, 0, 0, 0);
}
__device__ __forceinline__ bf16x8 cvt8(floatx4 v0, floatx4 v1) {
    bf16x8 a;
    a[0] = (__bf16)v0[0]; a[1] = (__bf16)v0[1]; a[2] = (__bf16)v0[2]; a[3] = (__bf16)v0[3];
    a[4] = (__bf16)v1[0]; a[5] = (__bf16)v1[1]; a[6] = (__bf16)v1[2]; a[7] = (__bf16)v1[3];
    return a;
}

// init-only full-grid spin (64-lane scan, used twice per launch)
__device__ __forceinline__ void ispin(unsigned long long tgt, int lane) {
    while (true) {
        unsigned long long v = ald8(&g_islot[lane * 8]);
        if (__all(v >= tgt)) break;
        __builtin_amdgcn_s_sleep(1);
    }
}

// steady-loop wait: lane0 polls own-layer progress, lane1 optionally layer0.
__device__ __forceinline__ void waitp(const unsigned long long* p0, unsigned long long t0,
                                      const unsigned long long* p1, unsigned long long t1,
                                      int lane) {
    while (true) {
        bool ok = true;
        if (lane == 0) ok = (ald8(p0) >= t0);
        else if (lane == 1 && p1) ok = (ald8(p1) >= t1);
        if (__all(ok)) break;
        __builtin_amdgcn_s_sleep(1);
    }
    __asm__ volatile("" ::: "memory");   // no load hoisting above the wait
}

__global__ __launch_bounds__(NTHR, 1) void gru_persist(
    const float* __restrict__ x,
    const float* __restrict__ Wr, const float* __restrict__ br,
    const float* __restrict__ Wu, const float* __restrict__ bu,
    const float* __restrict__ Wo, const float* __restrict__ bo,
    float* __restrict__ out)
{
    const int tid  = threadIdx.x;
    const int lane = tid & 63;
    const int widx = tid >> 6;          // 0=u, 1=r, 2=B(o/update), 3=leader/idle
    const int quad = lane >> 4;
    const int lo   = lane & 15;
    const int blk  = blockIdx.x;
    const int l    = blk >> 5;          // layer
    const int li   = blk & 31;          // layer-local block index = n-tile
    const int n0   = li * 16;

    __shared__ float lds_u[2][32][20];  // stride 20: 2-way banks (free)
    __shared__ int lds_ucnt;

    const unsigned long long base = ald8(&g_bcast[0][0]);  // all equal at entry
    unsigned long long iep = ald8(&g_islot[blk * 8]);
    if (tid == 0) lds_ucnt = 0;

    // ============ init phase 0: zero ring slot 0, cvt layer0 x-weights ======
    {
        int gtid = blk * NTHR + tid;
        unsigned* h0z = (unsigned*)&g_h0R[0][0];
        unsigned* h1z = (unsigned*)&g_h1R[0][0];
        for (int i = gtid; i < (Bn * Hn) / 2; i += NTHREADS) {
            h0z[i] = 0u;
            h1z[i] = 0u;
        }
        for (int i = gtid * 4; i < 3 * Dn * Hn; i += NTHREADS * 4) {
            int g = i / (Dn * Hn);
            int rem = i - g * (Dn * Hn);
            int n = rem >> 9, k = rem & 511;
            const float* ws = (g == 0) ? Wu : (g == 1) ? Wr : Wo;
            floatx4 v = *reinterpret_cast<const floatx4*>(ws + (size_t)n * KKn + k);
            ushort4 pk = make_ushort4(f2b(v[0]), f2b(v[1]), f2b(v[2]), f2b(v[3]));
            *reinterpret_cast<ushort4*>(&g_Wxb[0][0] + i) = pk;
        }
    }
    iep++;
    __syncthreads();
    if (tid == 0) { __threadfence(); ast8(&g_islot[blk * 8], iep); }
    ispin(iep, lane);
    if (widx == 0) __threadfence();
    __syncthreads();

    // ============ init phase 1: Xproj GEMM (layer0 x-projections) ===========
    {
        int gwave = blk * 4 + widx;     // 0..255
        for (int j = 0; j < 12; ++j) {
            int mt = gwave * 12 + j;    // 3072 m-tiles
            int g = mt >> 10;
            int rem = mt & 1023;
            int t = rem >> 1;
            int bh = (rem & 1) * 16;
            const float* xrow = x + (size_t)(bh + lo) * Tn * Dn + (size_t)t * Dn + quad * 8;
            bf16x8 af[16];
            #pragma unroll
            for (int i = 0; i < 16; ++i) {
                floatx4 v0 = *reinterpret_cast<const floatx4*>(xrow + i * 32);
                floatx4 v1 = *reinterpret_cast<const floatx4*>(xrow + i * 32 + 4);
                af[i] = cvt8(v0, v1);
            }
            for (int nt = 0; nt < 32; ++nt) {
                floatx4 acc = {0.f, 0.f, 0.f, 0.f};
                const unsigned short* wp = &g_Wxb[g][0] + (size_t)(nt * 16 + lo) * Dn + quad * 8;
                #pragma unroll
                for (int i = 0; i < 16; ++i)
                    acc = mfma(af[i], ldb8(wp + i * 32), acc);
                unsigned short* op = &g_Xproj[g][t][nt][0];
                #pragma unroll
                for (int rr = 0; rr < 4; ++rr)
                    op[(bh + quad * 4 + rr) * 16 + lo] = f2b(acc[rr]);
            }
        }
    }
    iep++;
    __syncthreads();
    if (tid == 0) { __threadfence(); ast8(&g_islot[blk * 8], iep); }
    ispin(iep, lane);
    if (widx == 0) __threadfence();
    __syncthreads();

    // ============ leader waves ============
    if (widx == 3) {
        if (blk == 0 || blk == 32) {
            const int ll = (blk == 32) ? 1 : 0;
            const unsigned long long fin = base + 2ull * Tn;
            unsigned long long cur = base;
            while (cur < fin) {
                unsigned long long v = (lane < 32) ? ald8(&g_slot[ll][lane]) : ~0ull;
                unsigned long long c = cur;
                while (c < fin && __all(v >= c + 1)) ++c;
                if (c != cur) { cur = c; ast8(&g_bcast[ll][0], cur); }
                else __builtin_amdgcn_s_sleep(1);
            }
        }
        return;
    }

    // ============ role setup: register-resident weights ============
    const float* Wsrc = (widx == 0) ? Wu : (widx == 1) ? Wr : Wo;
    const float bias = ((widx == 0) ? bu : (widx == 1) ? br : bo)[l * Hn + n0 + lo];
    const int nf = (l == 0) ? 16 : 32;
    bf16x8 wreg[32];
    {
        const int koff = (l == 0) ? Dn : 0;
        const float* wp = Wsrc + (size_t)l * Hn * KKn + (size_t)(n0 + lo) * KKn + koff + quad * 8;
        for (int i = 0; i < nf; ++i) {
            floatx4 v0 = *reinterpret_cast<const floatx4*>(wp + i * 32);
            floatx4 v1 = *reinterpret_cast<const floatx4*>(wp + i * 32 + 4);
            wreg[i] = cvt8(v0, v1);
        }
    }

    const unsigned long long* bcOwn = &g_bcast[l][0];
    const unsigned long long* bc0   = &g_bcast[0][0];
    unsigned long long* mySlot = &g_slot[l][li];

    float hreg0[4] = {0.f, 0.f, 0.f, 0.f};
    float hreg1[4] = {0.f, 0.f, 0.f, 0.f};

    // ============ steady free-running loop (512 layer-local steps) ==========
    for (int s = 0; s < Tn; ++s) {
        if (widx < 2) {
            // ---- A-wave (u or r) ----
            if (l == 0) waitp(bcOwn, base + 2 * s, nullptr, 0, lane);
            else        waitp(bcOwn, base + 2 * s, bc0, base + 2 * s + 2, lane);

            floatx4 a0, a1;
            const unsigned short* hsE;  // h for elementwise (r-wave)
            if (l == 0) {
                const unsigned short* xp = &g_Xproj[widx][s][li][0];
                #pragma unroll
                for (int rr = 0; rr < 4; ++rr) {
                    a0[rr] = b2fs(xp[(quad * 4 + rr) * 16 + lo]);
                    a1[rr] = b2fs(xp[(16 + quad * 4 + rr) * 16 + lo]);
                }
                const unsigned short* h = g_h0R[s];
                const unsigned short* p0 = h + (size_t)lo * Hn + quad * 8;
                const unsigned short* p1 = h + (size_t)(16 + lo) * Hn + quad * 8;
                #pragma unroll
                for (int i = 0; i < 16; ++i) {
                    a0 = mfma(ldb8(p0 + i * 32), wreg[i], a0);
                    a1 = mfma(ldb8(p1 + i * 32), wreg[i], a1);
                }
                hsE = h;
            } else {
                a0 = floatx4{0.f, 0.f, 0.f, 0.f}; a1 = a0;
                const unsigned short* hx = g_h0R[s + 1];
                const unsigned short* q0 = hx + (size_t)lo * Hn + quad * 8;
                const unsigned short* q1 = hx + (size_t)(16 + lo) * Hn + quad * 8;
                #pragma unroll
                for (int i = 0; i < 16; ++i) {
                    a0 = mfma(ldb8(q0 + i * 32), wreg[i], a0);
                    a1 = mfma(ldb8(q1 + i * 32), wreg[i], a1);
                }
                const unsigned short* h = g_h1R[s];
                const unsigned short* p0 = h + (size_t)lo * Hn + quad * 8;
                const unsigned short* p1 = h + (size_t)(16 + lo) * Hn + quad * 8;
                #pragma unroll
                for (int i = 0; i < 16; ++i) {
                    a0 = mfma(ldb8(p0 + i * 32), wreg[16 + i], a0);
                    a1 = mfma(ldb8(p1 + i * 32), wreg[16 + i], a1);
                }
                hsE = h;
            }
            if (widx == 0) {
                // u -> LDS mailbox
                int buf = s & 1;
                #pragma unroll
                for (int rr = 0; rr < 4; ++rr) {
                    int r0 = quad * 4 + rr;
                    lds_u[buf][r0][lo] = 1.f / (1.f + __expf(-(a0[rr] + bias)));
                    lds_u[buf][16 + r0][lo] = 1.f / (1.f + __expf(-(a1[rr] + bias)));
                }
                __threadfence_block();
                if (lane == 0)
                    __hip_atomic_store(&lds_ucnt, s + 1, __ATOMIC_RELAXED,
                                       __HIP_MEMORY_SCOPE_WORKGROUP);
            } else {
                // r -> hr ring (bypass publish), then arrival bump (alpha)
                unsigned short* hr = (l == 0) ? g_hr0R[s] : g_hr1R[s];
                #pragma unroll
                for (int rr = 0; rr < 4; ++rr) {
                    int r0 = quad * 4 + rr;
                    float rv0 = 1.f / (1.f + __expf(-(a0[rr] + bias)));
                    float rv1 = 1.f / (1.f + __expf(-(a1[rr] + bias)));
                    float hv0 = b2fs(hsE[(size_t)r0 * Hn + n0 + lo]);
                    float hv1 = b2fs(hsE[(size_t)(16 + r0) * Hn + n0 + lo]);
                    unsigned w0 = f2b(hv0 * rv0), w1 = f2b(hv1 * rv1);
                    unsigned p0 = (unsigned)__shfl_xor((int)w0, 1);
                    unsigned p1 = (unsigned)__shfl_xor((int)w1, 1);
                    if ((lo & 1) == 0) {
                        ast4u((unsigned*)(hr + (size_t)r0 * Hn + n0 + lo), w0 | (p0 << 16));
                        ast4u((unsigned*)(hr + (size_t)(16 + r0) * Hn + n0 + lo), w1 | (p1 << 16));
                    }
                }
                __asm__ volatile("s_waitcnt vmcnt(0)" ::: "memory");
                if (lane == 0) ast8(mySlot, base + 2 * s + 1);
            }
        } else {
            // ---- B-wave: prework (x-part), alpha wait, hr chain, update ----
            floatx4 a0 = {0.f, 0.f, 0.f, 0.f}, a1 = a0;
            if (l == 0) {
                const unsigned short* xp = &g_Xproj[2][s][li][0];
                #pragma unroll
                for (int rr = 0; rr < 4; ++rr) {
                    a0[rr] = b2fs(xp[(quad * 4 + rr) * 16 + lo]);
                    a1[rr] = b2fs(xp[(16 + quad * 4 + rr) * 16 + lo]);
                }
            } else {
                waitp(bc0, base + 2 * s + 2, nullptr, 0, lane);  // h0R[s+1] ready
                const unsigned short* hx = g_h0R[s + 1];
                const unsigned short* q0 = hx + (size_t)lo * Hn + quad * 8;
                const unsigned short* q1 = hx + (size_t)(16 + lo) * Hn + quad * 8;
                #pragma unroll
                for (int i = 0; i < 16; ++i) {
                    a0 = mfma(ldb8(q0 + i * 32), wreg[i], a0);
                    a1 = mfma(ldb8(q1 + i * 32), wreg[i], a1);
                }
            }
            waitp(bcOwn, base + 2 * s + 1, nullptr, 0, lane);    // alpha: hr ready
            while (__hip_atomic_load(&lds_ucnt, __ATOMIC_RELAXED,
                                     __HIP_MEMORY_SCOPE_WORKGROUP) < s + 1) {}
            __threadfence_block();

            const unsigned short* hr = (l == 0) ? g_hr0R[s] : g_hr1R[s];
            const unsigned short* p0 = hr + (size_t)lo * Hn + quad * 8;
            const unsigned short* p1 = hr + (size_t)(16 + lo) * Hn + quad * 8;
            const int wb = (l == 0) ? 0 : 16;
            #pragma unroll
            for (int i = 0; i < 16; ++i) {
                a0 = mfma(ldb8(p0 + i * 32), wreg[wb + i], a0);
                a1 = mfma(ldb8(p1 + i * 32), wreg[wb + i], a1);
            }
            unsigned short* hpub = (l == 0) ? g_h0R[s + 1] : g_h1R[s + 1];
            bool fin = (s == Tn - 1);
            int buf = s & 1;
            #pragma unroll
            for (int rr = 0; rr < 4; ++rr) {
                int r0 = quad * 4 + rr;
                size_t i0 = (size_t)r0 * Hn + n0 + lo;
                size_t i1 = (size_t)(16 + r0) * Hn + n0 + lo;
                float o0 = tanhf(a0[rr] + bias);
                float o1 = tanhf(a1[rr] + bias);
                float u0 = lds_u[buf][r0][lo];
                float u1 = lds_u[buf][16 + r0][lo];
                hreg0[rr] += u0 * (o0 - hreg0[rr]);
                hreg1[rr] += u1 * (o1 - hreg1[rr]);
                unsigned w0 = f2b(hreg0[rr]), w1 = f2b(hreg1[rr]);
                unsigned q0 = (unsigned)__shfl_xor((int)w0, 1);
                unsigned q1 = (unsigned)__shfl_xor((int)w1, 1);
                if ((lo & 1) == 0) {
                    ast4u((unsigned*)(hpub + i0), w0 | (q0 << 16));
                    ast4u((unsigned*)(hpub + i1), w1 | (q1 << 16));
                }
                if (fin) {
                    out[(size_t)l * Bn * Hn + i0] = hreg0[rr];
                    out[(size_t)l * Bn * Hn + i1] = hreg1[rr];
                }
            }
            __asm__ volatile("s_waitcnt vmcnt(0)" ::: "memory");
            if (lane == 0) ast8(mySlot, base + 2 * s + 2);
        }
    }
}

extern "C" void kernel_launch(void* const* d_in, const int* in_sizes, int n_in,
                              void* d_out, int out_size, void* d_ws, size_t ws_size,
                              hipStream_t stream) {
    const float* x  = (const float*)d_in[0];
    const float* Wr = (const float*)d_in[1];
    const float* br = (const float*)d_in[2];
    const float* Wu = (const float*)d_in[3];
    const float* bu = (const float*)d_in[4];
    const float* Wo = (const float*)d_in[5];
    const float* bo = (const float*)d_in[6];
    float* out = (float*)d_out;

    gru_persist<<<NBLK, NTHR, 0, stream>>>(x, Wr, br, Wu, bu, Wo, bo, out);
}

// Round 8
// 9003.255 us; speedup vs baseline: 1.1234x; 1.1234x over previous
//
#include <hip/hip_runtime.h>

// ConvGRU: 2-layer GRU, B=32, T=512, D=H=512, fp32 in/out, bf16 MFMA compute.
// Round-8: direct per-producer flags, fully decoupled layers, free-running.
//  - Write-once rings for h/hr (bypass publish, cached cold-miss consume).
//  - fA[l][s][i]: r-producer i's hr slice ready. fB[l][t][i]: h slice ready.
//    Consumers poll the 128B flag line with 16 lanes (1 coalesced request).
//  - No leader, no global barrier, no superstep lockstep: layer0 sprints,
//    layer1 chases through rings. One hop per dependency edge.

#define Bn 32
#define Tn 512
#define Dn 512
#define Hn 512
#define KKn 1024
#define NBLK 64
#define NTHR 192
#define NTHREADS (NBLK * NTHR)
#define RING (Tn + 2)

typedef __bf16 bf16x8 __attribute__((ext_vector_type(8)));
typedef float floatx4 __attribute__((ext_vector_type(4)));

// ---- persistent device state ----
__device__ unsigned short g_h0R[RING][Bn * Hn];
__device__ unsigned short g_h1R[RING][Bn * Hn];
__device__ unsigned short g_hr0R[Tn][Bn * Hn];
__device__ unsigned short g_hr1R[Tn][Bn * Hn];
__device__ unsigned short g_Xproj[3][Tn][32][Bn * 16]; // [g][t][ntile][row*16+lo]
__device__ unsigned short g_Wxb[3][Dn * Hn];           // layer0 x-half weights
__device__ unsigned g_fA[2][Tn][32];                   // hr ready flags
__device__ unsigned g_fB[2][Tn + 1][32];               // h ready flags
__device__ unsigned long long g_islot[NBLK * 8];       // init barrier (monotonic)

__device__ __forceinline__ bf16x8 ldb8(const unsigned short* p) {
    return *reinterpret_cast<const bf16x8*>(p);
}
__device__ __forceinline__ unsigned short f2b(float f) {
    union { float f; unsigned u; } v; v.f = f;
    unsigned u = v.u;
    return (unsigned short)((u + 0x7fffu + ((u >> 16) & 1u)) >> 16);  // RNE
}
__device__ __forceinline__ float b2fs(unsigned short b) {
    union { unsigned u; float f; } v; v.u = ((unsigned)b) << 16; return v.f;
}
__device__ __forceinline__ unsigned long long ald8(const void* p) {
    return __hip_atomic_load((const unsigned long long*)p, __ATOMIC_RELAXED,
                             __HIP_MEMORY_SCOPE_AGENT);
}
__device__ __forceinline__ void ast8(void* p, unsigned long long v) {
    __hip_atomic_store((unsigned long long*)p, v, __ATOMIC_RELAXED,
                       __HIP_MEMORY_SCOPE_AGENT);
}
__device__ __forceinline__ void ast4u(unsigned* p, unsigned v) {
    __hip_atomic_store(p, v, __ATOMIC_RELAXED, __HIP_MEMORY_SCOPE_AGENT);
}
__device__ __forceinline__ floatx4 mfma(bf16x8 a, bf16x8 b, floatx4 c) {
    return __builtin_amdgcn_mfma_f32_16x16x32_bf16(a, b, c, 0, 0, 0);
}
__device__ __forceinline__ bf16x8 cvt8(floatx4 v0, floatx4 v1) {
    bf16x8 a;
    a[0] = (__bf16)v0[0]; a[1] = (__bf16)v0[1]; a[2] = (__bf16)v0[2]; a[3] = (__bf16)v0[3];
    a[4] = (__bf16)v1[0]; a[5] = (__bf16)v1[1]; a[6] = (__bf16)v1[2]; a[7] = (__bf16)v1[3];
    return a;
}

// init-only full-grid spin
__device__ __forceinline__ void ispin(unsigned long long tgt, int lane) {
    while (true) {
        unsigned long long v = ald8(&g_islot[lane * 8]);
        if (__all(v >= tgt)) break;
        __builtin_amdgcn_s_sleep(1);
    }
}

// wait for all 32 producer flags of one (layer, step): 16 lanes scan 128B.
__device__ __forceinline__ void waitflags(const unsigned* f, int lane) {
    const unsigned long long* p = (const unsigned long long*)f;
    while (true) {
        bool ok = true;
        if (lane < 16) {
            unsigned long long v = ald8(&p[lane]);
            ok = ((unsigned)v != 0u) && ((unsigned)(v >> 32) != 0u);
        }
        if (__all(ok)) break;
        __builtin_amdgcn_s_sleep(1);
    }
    __asm__ volatile("" ::: "memory");   // no data-load hoisting above the wait
}

__global__ __launch_bounds__(NTHR, 1) void gru_persist(
    const float* __restrict__ x,
    const float* __restrict__ Wr, const float* __restrict__ br,
    const float* __restrict__ Wu, const float* __restrict__ bu,
    const float* __restrict__ Wo, const float* __restrict__ bo,
    float* __restrict__ out)
{
    const int tid  = threadIdx.x;
    const int lane = tid & 63;
    const int widx = tid >> 6;          // 0=u, 1=r, 2=B(o/update)
    const int quad = lane >> 4;
    const int lo   = lane & 15;
    const int blk  = blockIdx.x;
    const int l    = blk >> 5;          // layer
    const int li   = blk & 31;          // n-tile index
    const int n0   = li * 16;

    __shared__ float lds_u[2][32][20];
    __shared__ int lds_ucnt;

    unsigned long long iep = ald8(&g_islot[blk * 8]);
    if (tid == 0) lds_ucnt = 0;

    // ============ init phase 0: zero rings slot0 + ALL flags; cvt Wx =======
    {
        int gtid = blk * NTHR + tid;
        unsigned* h0z = (unsigned*)&g_h0R[0][0];
        unsigned* h1z = (unsigned*)&g_h1R[0][0];
        for (int i = gtid; i < (Bn * Hn) / 2; i += NTHREADS) {
            h0z[i] = 0u;
            h1z[i] = 0u;
        }
        unsigned* fa = &g_fA[0][0][0];
        for (int i = gtid; i < 2 * Tn * 32; i += NTHREADS) fa[i] = 0u;
        unsigned* fb = &g_fB[0][0][0];
        for (int i = gtid; i < 2 * (Tn + 1) * 32; i += NTHREADS) fb[i] = 0u;
        for (int i = gtid * 4; i < 3 * Dn * Hn; i += NTHREADS * 4) {
            int g = i / (Dn * Hn);
            int rem = i - g * (Dn * Hn);
            int n = rem >> 9, k = rem & 511;
            const float* ws = (g == 0) ? Wu : (g == 1) ? Wr : Wo;
            floatx4 v = *reinterpret_cast<const floatx4*>(ws + (size_t)n * KKn + k);
            ushort4 pk = make_ushort4(f2b(v[0]), f2b(v[1]), f2b(v[2]), f2b(v[3]));
            *reinterpret_cast<ushort4*>(&g_Wxb[0][0] + i) = pk;
        }
    }
    iep++;
    __syncthreads();
    if (tid == 0) { __threadfence(); ast8(&g_islot[blk * 8], iep); }
    ispin(iep, lane);
    if (widx == 0) __threadfence();
    __syncthreads();

    // ============ init phase 1: Xproj GEMM + set fB[l][0] = ready ==========
    {
        int gtid = blk * NTHR + tid;
        if (gtid < 64) g_fB[gtid >> 5][0][gtid & 31] = 1u;
        int gwave = blk * 3 + widx;     // 0..191
        for (int j = 0; j < 16; ++j) {
            int mt = gwave * 16 + j;    // 3072 m-tiles
            int g = mt >> 10;
            int rem = mt & 1023;
            int t = rem >> 1;
            int bh = (rem & 1) * 16;
            const float* xrow = x + (size_t)(bh + lo) * Tn * Dn + (size_t)t * Dn + quad * 8;
            bf16x8 af[16];
            #pragma unroll
            for (int i = 0; i < 16; ++i) {
                floatx4 v0 = *reinterpret_cast<const floatx4*>(xrow + i * 32);
                floatx4 v1 = *reinterpret_cast<const floatx4*>(xrow + i * 32 + 4);
                af[i] = cvt8(v0, v1);
            }
            for (int nt = 0; nt < 32; ++nt) {
                floatx4 acc = {0.f, 0.f, 0.f, 0.f};
                const unsigned short* wp = &g_Wxb[g][0] + (size_t)(nt * 16 + lo) * Dn + quad * 8;
                #pragma unroll
                for (int i = 0; i < 16; ++i)
                    acc = mfma(af[i], ldb8(wp + i * 32), acc);
                unsigned short* op = &g_Xproj[g][t][nt][0];
                #pragma unroll
                for (int rr = 0; rr < 4; ++rr)
                    op[(bh + quad * 4 + rr) * 16 + lo] = f2b(acc[rr]);
            }
        }
    }
    iep++;
    __syncthreads();
    if (tid == 0) { __threadfence(); ast8(&g_islot[blk * 8], iep); }
    ispin(iep, lane);
    if (widx == 0) __threadfence();
    __syncthreads();

    // ============ role setup: register-resident weights ============
    const float* Wsrc = (widx == 0) ? Wu : (widx == 1) ? Wr : Wo;
    const float bias = ((widx == 0) ? bu : (widx == 1) ? br : bo)[l * Hn + n0 + lo];
    const int nf = (l == 0) ? 16 : 32;
    bf16x8 wreg[32];
    {
        const int koff = (l == 0) ? Dn : 0;
        const float* wp = Wsrc + (size_t)l * Hn * KKn + (size_t)(n0 + lo) * KKn + koff + quad * 8;
        for (int i = 0; i < nf; ++i) {
            floatx4 v0 = *reinterpret_cast<const floatx4*>(wp + i * 32);
            floatx4 v1 = *reinterpret_cast<const floatx4*>(wp + i * 32 + 4);
            wreg[i] = cvt8(v0, v1);
        }
    }

    float hreg0[4] = {0.f, 0.f, 0.f, 0.f};
    float hreg1[4] = {0.f, 0.f, 0.f, 0.f};

    // ============ steady free-running loop (layer-local steps) =============
    for (int s = 0; s < Tn; ++s) {
        if (widx < 2) {
            // ---- A-wave (u or r) ----
            floatx4 a0, a1;
            const unsigned short* hsE;
            if (l == 0) {
                // launch-static Xproj read BEFORE any wait
                const unsigned short* xp = &g_Xproj[widx][s][li][0];
                #pragma unroll
                for (int rr = 0; rr < 4; ++rr) {
                    a0[rr] = b2fs(xp[(quad * 4 + rr) * 16 + lo]);
                    a1[rr] = b2fs(xp[(16 + quad * 4 + rr) * 16 + lo]);
                }
                waitflags(&g_fB[0][s][0], lane);
                const unsigned short* h = g_h0R[s];
                const unsigned short* p0 = h + (size_t)lo * Hn + quad * 8;
                const unsigned short* p1 = h + (size_t)(16 + lo) * Hn + quad * 8;
                #pragma unroll
                for (int i = 0; i < 16; ++i) {
                    a0 = mfma(ldb8(p0 + i * 32), wreg[i], a0);
                    a1 = mfma(ldb8(p1 + i * 32), wreg[i], a1);
                }
                hsE = h;
            } else {
                a0 = floatx4{0.f, 0.f, 0.f, 0.f}; a1 = a0;
                waitflags(&g_fB[0][s + 1][0], lane);   // usually long-set
                const unsigned short* hx = g_h0R[s + 1];
                const unsigned short* q0 = hx + (size_t)lo * Hn + quad * 8;
                const unsigned short* q1 = hx + (size_t)(16 + lo) * Hn + quad * 8;
                #pragma unroll
                for (int i = 0; i < 16; ++i) {
                    a0 = mfma(ldb8(q0 + i * 32), wreg[i], a0);
                    a1 = mfma(ldb8(q1 + i * 32), wreg[i], a1);
                }
                waitflags(&g_fB[1][s][0], lane);       // the real chain edge
                const unsigned short* h = g_h1R[s];
                const unsigned short* p0 = h + (size_t)lo * Hn + quad * 8;
                const unsigned short* p1 = h + (size_t)(16 + lo) * Hn + quad * 8;
                #pragma unroll
                for (int i = 0; i < 16; ++i) {
                    a0 = mfma(ldb8(p0 + i * 32), wreg[16 + i], a0);
                    a1 = mfma(ldb8(p1 + i * 32), wreg[16 + i], a1);
                }
                hsE = h;
            }
            if (widx == 0) {
                int buf = s & 1;
                #pragma unroll
                for (int rr = 0; rr < 4; ++rr) {
                    int r0 = quad * 4 + rr;
                    lds_u[buf][r0][lo] = 1.f / (1.f + __expf(-(a0[rr] + bias)));
                    lds_u[buf][16 + r0][lo] = 1.f / (1.f + __expf(-(a1[rr] + bias)));
                }
                __threadfence_block();
                if (lane == 0)
                    __hip_atomic_store(&lds_ucnt, s + 1, __ATOMIC_RELAXED,
                                       __HIP_MEMORY_SCOPE_WORKGROUP);
            } else {
                unsigned short* hr = (l == 0) ? g_hr0R[s] : g_hr1R[s];
                #pragma unroll
                for (int rr = 0; rr < 4; ++rr) {
                    int r0 = quad * 4 + rr;
                    float rv0 = 1.f / (1.f + __expf(-(a0[rr] + bias)));
                    float rv1 = 1.f / (1.f + __expf(-(a1[rr] + bias)));
                    float hv0 = b2fs(hsE[(size_t)r0 * Hn + n0 + lo]);
                    float hv1 = b2fs(hsE[(size_t)(16 + r0) * Hn + n0 + lo]);
                    unsigned w0 = f2b(hv0 * rv0), w1 = f2b(hv1 * rv1);
                    unsigned p0 = (unsigned)__shfl_xor((int)w0, 1);
                    unsigned p1 = (unsigned)__shfl_xor((int)w1, 1);
                    if ((lo & 1) == 0) {
                        ast4u((unsigned*)(hr + (size_t)r0 * Hn + n0 + lo), w0 | (p0 << 16));
                        ast4u((unsigned*)(hr + (size_t)(16 + r0) * Hn + n0 + lo), w1 | (p1 << 16));
                    }
                }
                __asm__ volatile("s_waitcnt vmcnt(0)" ::: "memory");
                if (lane == 0) ast4u(&g_fA[l][s][li], 1u);
            }
        } else {
            // ---- B-wave: x-part prework, fA wait, hr chain, update ----
            floatx4 a0 = {0.f, 0.f, 0.f, 0.f}, a1 = a0;
            if (l == 0) {
                const unsigned short* xp = &g_Xproj[2][s][li][0];
                #pragma unroll
                for (int rr = 0; rr < 4; ++rr) {
                    a0[rr] = b2fs(xp[(quad * 4 + rr) * 16 + lo]);
                    a1[rr] = b2fs(xp[(16 + quad * 4 + rr) * 16 + lo]);
                }
            } else {
                waitflags(&g_fB[0][s + 1][0], lane);   // usually long-set
                const unsigned short* hx = g_h0R[s + 1];
                const unsigned short* q0 = hx + (size_t)lo * Hn + quad * 8;
                const unsigned short* q1 = hx + (size_t)(16 + lo) * Hn + quad * 8;
                #pragma unroll
                for (int i = 0; i < 16; ++i) {
                    a0 = mfma(ldb8(q0 + i * 32), wreg[i], a0);
                    a1 = mfma(ldb8(q1 + i * 32), wreg[i], a1);
                }
            }
            waitflags(&g_fA[l][s][0], lane);
            while (__hip_atomic_load(&lds_ucnt, __ATOMIC_RELAXED,
                                     __HIP_MEMORY_SCOPE_WORKGROUP) < s + 1) {}
            __threadfence_block();

            const unsigned short* hr = (l == 0) ? g_hr0R[s] : g_hr1R[s];
            const unsigned short* p0 = hr + (size_t)lo * Hn + quad * 8;
            const unsigned short* p1 = hr + (size_t)(16 + lo) * Hn + quad * 8;
            const int wb = (l == 0) ? 0 : 16;
            #pragma unroll
            for (int i = 0; i < 16; ++i) {
                a0 = mfma(ldb8(p0 + i * 32), wreg[wb + i], a0);
                a1 = mfma(ldb8(p1 + i * 32), wreg[wb + i], a1);
            }
            unsigned short* hpub = (l == 0) ? g_h0R[s + 1] : g_h1R[s + 1];
            bool fin = (s == Tn - 1);
            int buf = s & 1;
            #pragma unroll
            for (int rr = 0; rr < 4; ++rr) {
                int r0 = quad * 4 + rr;
                size_t i0 = (size_t)r0 * Hn + n0 + lo;
                size_t i1 = (size_t)(16 + r0) * Hn + n0 + lo;
                float o0 = tanhf(a0[rr] + bias);
                float o1 = tanhf(a1[rr] + bias);
                float u0 = lds_u[buf][r0][lo];
                float u1 = lds_u[buf][16 + r0][lo];
                hreg0[rr] += u0 * (o0 - hreg0[rr]);
                hreg1[rr] += u1 * (o1 - hreg1[rr]);
                unsigned w0 = f2b(hreg0[rr]), w1 = f2b(hreg1[rr]);
                unsigned q0 = (unsigned)__shfl_xor((int)w0, 1);
                unsigned q1 = (unsigned)__shfl_xor((int)w1, 1);
                if ((lo & 1) == 0) {
                    ast4u((unsigned*)(hpub + i0), w0 | (q0 << 16));
                    ast4u((unsigned*)(hpub + i1), w1 | (q1 << 16));
                }
            }
            __asm__ volatile("s_waitcnt vmcnt(0)" ::: "memory");
            if (lane == 0) ast4u(&g_fB[l][s + 1][li], 1u);
            if (fin) {
                #pragma unroll
                for (int rr = 0; rr < 4; ++rr) {
                    int r0 = quad * 4 + rr;
                    size_t i0 = (size_t)r0 * Hn + n0 + lo;
                    size_t i1 = (size_t)(16 + r0) * Hn + n0 + lo;
                    out[(size_t)l * Bn * Hn + i0] = hreg0[rr];
                    out[(size_t)l * Bn * Hn + i1] = hreg1[rr];
                }
            }
        }
    }
}

extern "C" void kernel_launch(void* const* d_in, const int* in_sizes, int n_in,
                              void* d_out, int out_size, void* d_ws, size_t ws_size,
                              hipStream_t stream) {
    const float* x  = (const float*)d_in[0];
    const float* Wr = (const float*)d_in[1];
    const float* br = (const float*)d_in[2];
    const float* Wu = (const float*)d_in[3];
    const float* bu = (const float*)d_in[4];
    const float* Wo = (const float*)d_in[5];
    const float* bo = (const float*)d_in[6];
    float* out = (float*)d_out;

    gru_persist<<<NBLK, NTHR, 0, stream>>>(x, Wr, br, Wu, bu, Wo, bo, out);
}